// Round 3
// baseline (244.860 us; speedup 1.0000x reference)
//
#include <hip/hip_runtime.h>

// dense_image_warp: B=8, H=512, W=512, C=16, fp32.
// One thread per PAIR of (b,y,x,cg) items: item tid and item tid+HALF.
// Item bit layout: [b:3][y:9][x:9][cg:2]; cg indexes a float4 channel group.
// Consecutive lanes cover the 4 channel groups of one pixel -> each corner
// gather is a 64B contiguous segment; output stores fully coalesced.
// 2x items per thread doubles in-flight gathers (latency-bound workload).

#define HALF (8 * 512 * 512 * 4 / 2)   // 4,194,304 float4 items per half

typedef float vf4 __attribute__((ext_vector_type(4)));
typedef float vf2 __attribute__((ext_vector_type(2)));

__device__ __forceinline__ void decode(int i, int& pix, int& y, int& x, int& cg)
{
    cg = i & 3;
    x  = (i >> 2) & 511;
    y  = (i >> 11) & 511;
    const int b = i >> 20;
    pix = (((b << 9) + y) << 9) + x;
}

__device__ __forceinline__ const float* corner_base(
    const float* img, const vf2 f, int y, int x, int pix, int cg,
    float& ay, float& ax)
{
    const float qy = (float)y - f.x;
    const float qx = (float)x - f.y;
    float fy = floorf(qy); fy = fminf(fmaxf(fy, 0.0f), 510.0f);
    float fx = floorf(qx); fx = fminf(fmaxf(fx, 0.0f), 510.0f);
    ay = fminf(fmaxf(qy - fy, 0.0f), 1.0f);
    ax = fminf(fmaxf(qx - fx, 0.0f), 1.0f);
    const int iy = (int)fy;
    const int ix = (int)fx;
    const int bimg = pix - (((y << 9) + x) - ((iy << 9) + ix));  // b*512*512 + iy*512 + ix
    return img + (size_t)bimg * 16 + (cg << 2);
}

__device__ __forceinline__ vf4 lerp2d(vf4 tl, vf4 tr, vf4 bl, vf4 br,
                                      float ax, float ay)
{
    const vf4 top = tl + ax * (tr - tl);
    const vf4 bot = bl + ax * (br - bl);
    return top + ay * (bot - top);
}

__global__ __launch_bounds__(256) void warp_kernel(
    const float* __restrict__ img,
    const float* __restrict__ flow,
    float* __restrict__ out)
{
    const int tid = blockIdx.x * blockDim.x + threadIdx.x;
    const int i0 = tid;
    const int i1 = tid + HALF;

    int pix0, y0, x0, cg0, pix1, y1, x1, cg1;
    decode(i0, pix0, y0, x0, cg0);
    decode(i1, pix1, y1, x1, cg1);

    // Issue both flow loads up front (independent).
    const vf2 f0 = __builtin_nontemporal_load(&((const vf2*)flow)[pix0]);
    const vf2 f1 = __builtin_nontemporal_load(&((const vf2*)flow)[pix1]);

    float ay0, ax0, ay1, ax1;
    const float* p0 = corner_base(img, f0, y0, x0, pix0, cg0, ay0, ax0);
    const float* p1 = corner_base(img, f1, y1, x1, pix1, cg1, ay1, ax1);

    // 8 independent gathers in flight.
    const vf4 tl0 = *(const vf4*)(p0);
    const vf4 tr0 = *(const vf4*)(p0 + 16);
    const vf4 bl0 = *(const vf4*)(p0 + 512 * 16);
    const vf4 br0 = *(const vf4*)(p0 + 512 * 16 + 16);
    const vf4 tl1 = *(const vf4*)(p1);
    const vf4 tr1 = *(const vf4*)(p1 + 16);
    const vf4 bl1 = *(const vf4*)(p1 + 512 * 16);
    const vf4 br1 = *(const vf4*)(p1 + 512 * 16 + 16);

    const vf4 r0 = lerp2d(tl0, tr0, bl0, br0, ax0, ay0);
    const vf4 r1 = lerp2d(tl1, tr1, bl1, br1, ax1, ay1);

    __builtin_nontemporal_store(r0, &((vf4*)out)[i0]);
    __builtin_nontemporal_store(r1, &((vf4*)out)[i1]);
}

extern "C" void kernel_launch(void* const* d_in, const int* in_sizes, int n_in,
                              void* d_out, int out_size, void* d_ws, size_t ws_size,
                              hipStream_t stream) {
    const float* img  = (const float*)d_in[0];
    const float* flow = (const float*)d_in[1];
    float* out = (float*)d_out;

    const int block = 256;
    const int grid = HALF / block;   // 16384 blocks
    warp_kernel<<<grid, block, 0, stream>>>(img, flow, out);
}